// Round 2
// baseline (1138.458 us; speedup 1.0000x reference)
//
#include <hip/hip_runtime.h>
#include <math.h>

typedef __bf16 bf16;
typedef __attribute__((ext_vector_type(8))) __bf16 bf16x8;
typedef __attribute__((ext_vector_type(4))) float f32x4;

#define T_STEPS 128
#define B_SZ    256
#define V_SZ    256
#define N_SZ    1024
#define NROWS   (T_STEPS * B_SZ)   // 32768
#define NGRP    16                 // row groups (16 batch rows each)
#define NTILE   64                 // 16-col tiles per group (64 * 16 = 1024)

__device__ __forceinline__ float fast_tanh(float x) {
    float e = __expf(2.0f * x);
    return 1.0f - 2.0f / (e + 1.0f);   // exact at +-inf, no NaN
}

__device__ __forceinline__ bf16x8 cvt_bf16x8(float4 a, float4 b) {
    bf16x8 r;
    r[0] = (bf16)a.x; r[1] = (bf16)a.y; r[2] = (bf16)a.z; r[3] = (bf16)a.w;
    r[4] = (bf16)b.x; r[5] = (bf16)b.y; r[6] = (bf16)b.z; r[7] = (bf16)b.w;
    return r;
}

// ---------------- one-shot prep: all three fp32->bf16 transposes -------------------
__global__ __launch_bounds__(256) void k_prep(
    const float* __restrict__ weights,   // (V+N) x N  = 1280 x 1024
    const float* __restrict__ out_w,     // N x V      = 1024 x 256
    bf16* __restrict__ Wxt,              // 1024 x 256
    bf16* __restrict__ Wht,              // 1024 x 1024
    bf16* __restrict__ Wot)              // 256 x 1024
{
    __shared__ float tile[32][33];
    int id = blockIdx.x;
    const float* src; bf16* dst; int R, C, tr, tc;
    if (id < 256) {            // Wx: rows 0..255 of weights -> Wxt
        src = weights; dst = Wxt; R = V_SZ; C = N_SZ;
        tr = (id & 7) * 32; tc = (id >> 3) * 32;
    } else if (id < 1280) {    // Wh: rows 256..1279 of weights -> Wht
        id -= 256;
        src = weights + (size_t)V_SZ * N_SZ; dst = Wht; R = N_SZ; C = N_SZ;
        tr = (id & 31) * 32; tc = (id >> 5) * 32;
    } else {                   // Wo: out_w -> Wot
        id -= 1280;
        src = out_w; dst = Wot; R = N_SZ; C = V_SZ;
        tr = (id & 31) * 32; tc = (id >> 5) * 32;
    }
    int tx = threadIdx.x & 31;
    int ty = threadIdx.x >> 5;   // 0..7
#pragma unroll
    for (int i = 0; i < 32; i += 8)
        tile[ty + i][tx] = src[(size_t)(tr + ty + i) * C + tc + tx];
    __syncthreads();
#pragma unroll
    for (int i = 0; i < 32; i += 8)
        dst[(size_t)(tc + ty + i) * R + tr + tx] = (bf16)tile[tx][ty + i];
}

// ---------------- persistent recurrence: per-wave FULL-K tiles ---------------------
// R13 restructure: each wave owns one (group g, 16-col tile nt) output and the FULL
// K=1024 dot product. NO cross-wave reduction => no LDS, no __syncthreads in the
// loop. 1024 waves = 256 blocks x 4 waves (1 block/CU, 1 wave/SIMD; up to 512 VGPR).
// Sync: 64 flags per group; lane i polls flag i (one coalesced load + __all).
// MFMA operands SWAPPED (mfma(b,a)): D row = Wht-row = output col, D col(l15) =
// H row => each lane holds 4 consecutive output cols of ONE row -> one 8B store.
// Correctness: flag observed >= t  =>  producer drained vmcnt(0) after agent-scope
// H stores => plane t-1 at L3; consumer A-loads are first-touch per XCD (addresses
// never cached before this step) => no stale L2 possible.
__global__ __launch_bounds__(256, 1) void k_rnn(
    const float* __restrict__ Xf,   // 32768 x 256 fp32 inputs (t-major)
    const bf16* __restrict__ Wxt,   // 1024 x 256  = Wx^T
    const bf16* __restrict__ Wht,   // 1024 x 1024 = Wh^T
    const float* __restrict__ bias,
    bf16* __restrict__ XH,          // 32768 x 1024 H states
    int* __restrict__ flg)          // [NGRP][NTILE], zeroed; value = planes done
{
    const int tid  = threadIdx.x;
    const int lane = tid & 63;
    const int w    = tid >> 6;        // 0..3
    const int quad = lane >> 4;
    const int l15  = lane & 15;
    const int g    = blockIdx.x >> 4;            // 0..15
    const int nt   = (blockIdx.x & 15) * 4 + w;  // 0..63
    const int m0   = g * 16;
    const int n0   = nt * 16;
    int* gflg = flg + g * NTILE;

    // hoisted B fragments: Wht rows n0..n0+15 (= output cols), full K=1024
    bf16x8 b[32];
#pragma unroll
    for (int kc = 0; kc < 32; ++kc)
        b[kc] = *(const bf16x8*)&Wht[(size_t)(n0 + l15) * N_SZ + kc * 32 + quad * 8];
    bf16x8 bx[8];
#pragma unroll
    for (int kc = 0; kc < 8; ++kc)
        bx[kc] = *(const bf16x8*)&Wxt[(size_t)(n0 + l15) * V_SZ + kc * 32 + quad * 8];
    const float4 bias4 = *(const float4*)&bias[n0 + quad * 4];

    const size_t xbase = (size_t)(m0 + l15) * V_SZ + quad * 8;
    // element offset of this lane's 4 outputs within one plane
    const size_t hoff  = (size_t)(m0 + l15) * N_SZ + n0 + quad * 4;
    const f32x4 zz = {0.f, 0.f, 0.f, 0.f};

    // ---------------- t = 0: H_0 = tanh(Xproj_0 + bias) ----------------
    {
        f32x4 acc0 = zz, acc1 = zz;
#pragma unroll
        for (int kc = 0; kc < 8; ++kc) {
            float4 f0 = *(const float4*)&Xf[xbase + kc * 32];
            float4 f1 = *(const float4*)&Xf[xbase + kc * 32 + 4];
            bf16x8 ax = cvt_bf16x8(f0, f1);
            if (kc & 1) acc1 = __builtin_amdgcn_mfma_f32_16x16x32_bf16(bx[kc], ax, acc1, 0, 0, 0);
            else        acc0 = __builtin_amdgcn_mfma_f32_16x16x32_bf16(bx[kc], ax, acc0, 0, 0, 0);
        }
        float s0 = acc0[0] + acc1[0] + bias4.x;
        float s1 = acc0[1] + acc1[1] + bias4.y;
        float s2 = acc0[2] + acc1[2] + bias4.z;
        float s3 = acc0[3] + acc1[3] + bias4.w;
        bf16 h0 = (bf16)fast_tanh(s0), h1 = (bf16)fast_tanh(s1);
        bf16 h2 = (bf16)fast_tanh(s2), h3 = (bf16)fast_tanh(s3);
        unsigned int lo = (unsigned int)__builtin_bit_cast(unsigned short, h0)
                        | ((unsigned int)__builtin_bit_cast(unsigned short, h1) << 16);
        unsigned int hi = (unsigned int)__builtin_bit_cast(unsigned short, h2)
                        | ((unsigned int)__builtin_bit_cast(unsigned short, h3) << 16);
        unsigned long long pk = (unsigned long long)lo | ((unsigned long long)hi << 32);
        __hip_atomic_store((unsigned long long*)(XH + hoff), pk,
                           __ATOMIC_RELAXED, __HIP_MEMORY_SCOPE_AGENT);
        asm volatile("s_waitcnt vmcnt(0)" ::: "memory");
        if (lane == 0)
            __hip_atomic_store(&gflg[nt], 1, __ATOMIC_RELAXED, __HIP_MEMORY_SCOPE_AGENT);
    }

    // ---------------- t = 1 .. 127 ----------------
    for (int t = 1; t < T_STEPS; ++t) {
        // Xproj (no H dependency): loads + 8 MFMAs BEFORE the poll
        f32x4 acc0 = zz, acc1 = zz;
        const float* xp = &Xf[(size_t)t * B_SZ * V_SZ + xbase];
#pragma unroll
        for (int kc = 0; kc < 8; ++kc) {
            float4 f0 = *(const float4*)&xp[kc * 32];
            float4 f1 = *(const float4*)&xp[kc * 32 + 4];
            bf16x8 ax = cvt_bf16x8(f0, f1);
            if (kc & 1) acc1 = __builtin_amdgcn_mfma_f32_16x16x32_bf16(bx[kc], ax, acc1, 0, 0, 0);
            else        acc0 = __builtin_amdgcn_mfma_f32_16x16x32_bf16(bx[kc], ax, acc0, 0, 0, 0);
        }
        // pin Xproj before the poll (prevent sinking past the spin loop)
        asm volatile("" : "+v"(acc0), "+v"(acc1) :: "memory");

        // group barrier: lane i polls flag i until all 64 producers published t-1
        while (true) {
            int v = __hip_atomic_load(&gflg[lane], __ATOMIC_RELAXED,
                                      __HIP_MEMORY_SCOPE_AGENT);
            if (__all(v >= t)) break;
            __builtin_amdgcn_s_sleep(1);
        }
        asm volatile("" ::: "memory");

        // A fragments: this lane's H row (m0+l15) of plane t-1, full K
        const bf16* Ap = XH + ((size_t)(t - 1) * B_SZ + m0 + l15) * N_SZ + quad * 8;
        bf16x8 a[32];
#pragma unroll
        for (int kc = 0; kc < 32; ++kc)
            a[kc] = *(const bf16x8*)&Ap[kc * 32];
#pragma unroll
        for (int kc = 0; kc < 32; ++kc) {
            if (kc & 1) acc1 = __builtin_amdgcn_mfma_f32_16x16x32_bf16(b[kc], a[kc], acc1, 0, 0, 0);
            else        acc0 = __builtin_amdgcn_mfma_f32_16x16x32_bf16(b[kc], a[kc], acc0, 0, 0, 0);
        }

        // epilogue: 4 consecutive cols of row m0+l15 -> one 8B agent store
        float s0 = acc0[0] + acc1[0] + bias4.x;
        float s1 = acc0[1] + acc1[1] + bias4.y;
        float s2 = acc0[2] + acc1[2] + bias4.z;
        float s3 = acc0[3] + acc1[3] + bias4.w;
        bf16 h0 = (bf16)fast_tanh(s0), h1 = (bf16)fast_tanh(s1);
        bf16 h2 = (bf16)fast_tanh(s2), h3 = (bf16)fast_tanh(s3);
        unsigned int lo = (unsigned int)__builtin_bit_cast(unsigned short, h0)
                        | ((unsigned int)__builtin_bit_cast(unsigned short, h1) << 16);
        unsigned int hi = (unsigned int)__builtin_bit_cast(unsigned short, h2)
                        | ((unsigned int)__builtin_bit_cast(unsigned short, h3) << 16);
        unsigned long long pk = (unsigned long long)lo | ((unsigned long long)hi << 32);
        __hip_atomic_store((unsigned long long*)(XH + (size_t)t * B_SZ * N_SZ + hoff), pk,
                           __ATOMIC_RELAXED, __HIP_MEMORY_SCOPE_AGENT);
        asm volatile("s_waitcnt vmcnt(0)" ::: "memory");
        if (lane == 0)
            __hip_atomic_store(&gflg[nt], t + 1, __ATOMIC_RELAXED, __HIP_MEMORY_SCOPE_AGENT);
    }
}

// ---------------- fused loss: logits GEMM + log-softmax + label dot ----------------
// 512 blocks x 256 threads; block owns 64 rows x all 256 vocab cols, K=1024.
// Wave w: cols w*64..w*64+63 (4 col-tiles) x 4 row-tiles -> 16 accs, 512 MFMAs.
// Logits go GEMM -> LDS -> softmax; they never touch global memory.
// Labels prefetched to registers before the GEMM (HBM latency hidden).
__global__ __launch_bounds__(256, 2) void k_loss(
    const bf16*  __restrict__ XH,     // 32768 x 1024
    const bf16*  __restrict__ Wot,    // 256 x 1024 = Wo^T
    const float* __restrict__ labels, // 32768 x 256
    const float* __restrict__ ob,     // 256
    float* __restrict__ out)
{
    __shared__ float lg[64][260];     // 66.6 KB logits (stride 260 keeps 16B align)
    __shared__ float bt[4];
    const int tid  = threadIdx.x;
    const int lane = tid & 63;
    const int w    = tid >> 6;       // 0..3
    const int quad = lane >> 4;
    const int l15  = lane & 15;
    const int r0   = blockIdx.x * 64;

    // label prefetch: this thread owns row prow, quarter q (64 cols)
    const int prow = w * 16 + (lane >> 2);   // 0..63
    const int q    = lane & 3;
    float4 lb[16];
#pragma unroll
    for (int i = 0; i < 16; ++i)
        lb[i] = *(const float4*)&labels[(size_t)(r0 + prow) * V_SZ + q * 64 + i * 4];

    float obv[4];
#pragma unroll
    for (int ct = 0; ct < 4; ++ct)
        obv[ct] = ob[(w * 4 + ct) * 16 + l15];

    f32x4 acc[4][4];                 // [row-tile][col-tile]
#pragma unroll
    for (int rt = 0; rt < 4; ++rt)
#pragma unroll
        for (int ct = 0; ct < 4; ++ct)
            acc[rt][ct] = (f32x4){0.f, 0.f, 0.f, 0.f};

#pragma unroll 4
    for (int kc = 0; kc < 32; ++kc) {
        bf16x8 a[4], bo[4];
#pragma unroll
        for (int rt = 0; rt < 4; ++rt)
            a[rt] = *(const bf16x8*)&XH[(size_t)(r0 + rt * 16 + l15) * N_SZ + kc * 32 + quad * 8];
#pragma unroll
        for (int ct = 0; ct < 4; ++ct)
            bo[ct] = *(const bf16x8*)&Wot[(size_t)((w * 4 + ct) * 16 + l15) * N_SZ + kc * 32 + quad * 8];
#pragma unroll
        for (int rt = 0; rt < 4; ++rt)
#pragma unroll
            for (int ct = 0; ct < 4; ++ct)
                acc[rt][ct] = __builtin_amdgcn_mfma_f32_16x16x32_bf16(a[rt], bo[ct],
                                                                      acc[rt][ct], 0, 0, 0);
    }
    // D layout: col = l15 (vocab col within tile), row = quad*4 + r (H row in tile)
#pragma unroll
    for (int rt = 0; rt < 4; ++rt)
#pragma unroll
        for (int ct = 0; ct < 4; ++ct)
#pragma unroll
            for (int r = 0; r < 4; ++r)
                lg[rt * 16 + quad * 4 + r][(w * 4 + ct) * 16 + l15] = acc[rt][ct][r] + obv[ct];
    __syncthreads();

    // phase 2: per-row log-softmax + label dot; 4 threads per row (64 cols each)
    float mx = -1e30f;
#pragma unroll
    for (int i = 0; i < 16; ++i) {
        float4 v = *(const float4*)&lg[prow][q * 64 + i * 4];
        mx = fmaxf(mx, fmaxf(fmaxf(v.x, v.y), fmaxf(v.z, v.w)));
    }
    mx = fmaxf(mx, __shfl_xor(mx, 1, 64));
    mx = fmaxf(mx, __shfl_xor(mx, 2, 64));
    float se = 0.f, labs = 0.f, labv = 0.f;
#pragma unroll
    for (int i = 0; i < 16; ++i) {
        float4 v = *(const float4*)&lg[prow][q * 64 + i * 4];
        se += __expf(v.x - mx) + __expf(v.y - mx) + __expf(v.z - mx) + __expf(v.w - mx);
        float4 l = lb[i];
        labs += l.x + l.y + l.z + l.w;
        labv += l.x * v.x + l.y * v.y + l.z * v.z + l.w * v.w;
    }
#pragma unroll
    for (int s = 1; s < 4; s <<= 1) {
        se   += __shfl_xor(se, s, 64);
        labs += __shfl_xor(labs, s, 64);
        labv += __shfl_xor(labv, s, 64);
    }
    float wt = (q == 0) ? (labs * (mx + __logf(se)) - labv) : 0.f;
#pragma unroll
    for (int s = 4; s < 64; s <<= 1)
        wt += __shfl_xor(wt, s, 64);
    if (lane == 0) bt[w] = wt;
    __syncthreads();
    if (tid == 0)
        atomicAdd(out, (bt[0] + bt[1] + bt[2] + bt[3]) * (1.0f / (float)NROWS));
}

extern "C" void kernel_launch(void* const* d_in, const int* in_sizes, int n_in,
                              void* d_out, int out_size, void* d_ws, size_t ws_size,
                              hipStream_t stream)
{
    const float* inputs  = (const float*)d_in[0];
    const float* labels  = (const float*)d_in[1];
    const float* weights = (const float*)d_in[2];
    const float* bias    = (const float*)d_in[3];
    const float* out_w   = (const float*)d_in[4];
    const float* out_b   = (const float*)d_in[5];
    float* out = (float*)d_out;

    char* ws = (char*)d_ws;
    bf16* XH  = (bf16*)ws;  ws += (size_t)NROWS * N_SZ * 2;   // 64 MB H states
    bf16* Wxt = (bf16*)ws;  ws += (size_t)N_SZ * V_SZ * 2;    // 0.5 MB (Wx^T)
    bf16* Wht = (bf16*)ws;  ws += (size_t)N_SZ * N_SZ * 2;    // 2 MB   (Wh^T)
    bf16* Wot = (bf16*)ws;  ws += (size_t)V_SZ * N_SZ * 2;    // 0.5 MB (Wo^T)
    int*  flg = (int*)ws;   ws += (size_t)NGRP * NTILE * 4;   // 4 KB flags

    hipMemsetAsync(out, 0, sizeof(float), stream);
    hipMemsetAsync(flg, 0, (size_t)NGRP * NTILE * 4, stream);

    k_prep<<<dim3(1536), 256, 0, stream>>>(weights, out_w, Wxt, Wht, Wot);

    k_rnn<<<dim3(256), 256, 0, stream>>>(inputs, Wxt, Wht, bias, XH, flg);

    k_loss<<<dim3(NROWS / 64), 256, 0, stream>>>(XH, Wot, labels, out_b, out);
}

// Round 3
// 494.630 us; speedup vs baseline: 2.3016x; 2.3016x over previous
//
#include <hip/hip_runtime.h>
#include <math.h>

typedef __bf16 bf16;
typedef __attribute__((ext_vector_type(4))) __bf16 bf16x4;
typedef __attribute__((ext_vector_type(8))) __bf16 bf16x8;
typedef __attribute__((ext_vector_type(4))) float f32x4;

#define T_STEPS 128
#define B_SZ    256
#define V_SZ    256
#define N_SZ    1024
#define NROWS   (T_STEPS * B_SZ)   // 32768
#define RSTR    68                 // step reduction stride (floats)
#define LSTR    17                 // loss reduction stride (floats)
#define NGRP    16                 // row groups (16 batch rows each)
#define NCB     16                 // col blocks per group (64 cols each)

__device__ __forceinline__ float fast_tanh(float x) {
    float e = __expf(2.0f * x);
    return 1.0f - 2.0f / (e + 1.0f);   // exact at +-inf, no NaN
}

__device__ __forceinline__ bf16x8 cvt_bf16x8(float4 a, float4 b) {
    bf16x8 r;
    r[0] = (bf16)a.x; r[1] = (bf16)a.y; r[2] = (bf16)a.z; r[3] = (bf16)a.w;
    r[4] = (bf16)b.x; r[5] = (bf16)b.y; r[6] = (bf16)b.z; r[7] = (bf16)b.w;
    return r;
}

// ---------------- one-shot prep: all three fp32->bf16 transposes -------------------
__global__ __launch_bounds__(256) void k_prep(
    const float* __restrict__ weights,   // (V+N) x N  = 1280 x 1024
    const float* __restrict__ out_w,     // N x V      = 1024 x 256
    bf16* __restrict__ Wxt,              // 1024 x 256
    bf16* __restrict__ Wht,              // 1024 x 1024
    bf16* __restrict__ Wot)              // 256 x 1024
{
    __shared__ float tile[32][33];
    int id = blockIdx.x;
    const float* src; bf16* dst; int R, C, tr, tc;
    if (id < 256) {            // Wx: rows 0..255 of weights -> Wxt
        src = weights; dst = Wxt; R = V_SZ; C = N_SZ;
        tr = (id & 7) * 32; tc = (id >> 3) * 32;
    } else if (id < 1280) {    // Wh: rows 256..1279 of weights -> Wht
        id -= 256;
        src = weights + (size_t)V_SZ * N_SZ; dst = Wht; R = N_SZ; C = N_SZ;
        tr = (id & 31) * 32; tc = (id >> 5) * 32;
    } else {                   // Wo: out_w -> Wot
        id -= 1280;
        src = out_w; dst = Wot; R = N_SZ; C = V_SZ;
        tr = (id & 31) * 32; tc = (id >> 5) * 32;
    }
    int tx = threadIdx.x & 31;
    int ty = threadIdx.x >> 5;   // 0..7
#pragma unroll
    for (int i = 0; i < 32; i += 8)
        tile[ty + i][tx] = src[(size_t)(tr + ty + i) * C + tc + tx];
    __syncthreads();
#pragma unroll
    for (int i = 0; i < 32; i += 8)
        dst[(size_t)(tc + ty + i) * R + tr + tx] = (bf16)tile[tx][ty + i];
}

// ---------------- persistent recurrence + fused Xproj + fused loss GEMM ------------
// R14 = proven R11 structure (counter sync, 16 arrivals, K split across 8 waves,
// LDS K-reduce, in-loop loss GEMM) with three latency cuts on the per-step chain:
//   (1) counter load issued at loop top; Xproj cvt+MFMAs execute BEFORE the check
//       => the poll RTT is hidden under useful work.
//   (2) per-wave uniform poll (all lanes, one line) + NO release barrier — WAR on
//       red/lred is already ordered by barrier #B of the previous iteration.
//   (3) vmcnt(1) before #B: the logit store (newest VMEM op, unread in-kernel)
//       may stay in flight; in-order retirement still proves the H-store drained.
__global__ __launch_bounds__(512, 2) void k_rnn(
    const float* __restrict__ Xf,   // 32768 x 256 fp32 inputs (t-major)
    const bf16* __restrict__ Wxt,   // 1024 x 256  = Wx^T
    const bf16* __restrict__ Wht,   // 1024 x 1024 = Wh^T
    const bf16* __restrict__ Wot,   // 256 x 1024  = Wo^T
    const float* __restrict__ bias,
    bf16* __restrict__ XH,          // 32768 x 1024 H states
    unsigned int* __restrict__ Lgu, // bf16-pair logits, slab layout [p][c][256][8]
    int* __restrict__ cnt)          // [NGRP * T_STEPS], zeroed
{
    __shared__ float red[8 * 16 * RSTR];   // 34.8 KB step K-reduce
    __shared__ float lred[8 * 16 * LSTR];  // 8.7 KB  loss K-reduce
    const int tid  = threadIdx.x;
    const int lane = tid & 63;
    const int w    = tid >> 6;        // 0..7
    const int quad = lane >> 4;
    const int l15  = lane & 15;
    const int g  = blockIdx.x >> 4;   // row group
    const int c  = blockIdx.x & 15;   // col block / vocab slab
    const int m0 = g * 16;
    const int n0 = c * 64;
    const int k0 = w * 128;           // K-slice for Wh / Wot GEMMs
    const int v0 = w * 32;            // K-slice for Xproj GEMM (V=256 / 8)
    int* gcnt = cnt + g * T_STEPS;

    // hoisted B fragments (reloads come from hot L2 — never invalidated)
    const bf16* Bp = Wht + (size_t)(n0 + l15) * N_SZ + k0 + quad * 8;
    bf16x8 b[4][4];
#pragma unroll
    for (int nt = 0; nt < 4; ++nt)
#pragma unroll
        for (int kc = 0; kc < 4; ++kc)
            b[nt][kc] = *(const bf16x8*)&Bp[(size_t)(nt * 16) * N_SZ + kc * 32];
    bf16x8 bx[4];
#pragma unroll
    for (int nt = 0; nt < 4; ++nt)
        bx[nt] = *(const bf16x8*)&Wxt[(size_t)(n0 + nt * 16 + l15) * V_SZ + v0 + quad * 8];
    bf16x8 bo[4];
#pragma unroll
    for (int kc = 0; kc < 4; ++kc)
        bo[kc] = *(const bf16x8*)&Wot[(size_t)(c * 16 + l15) * N_SZ + k0 + kc * 32 + quad * 8];

    const int orow = tid >> 5;           // 0..15
    const int ocol = (tid & 31) * 2;     // 0..62
    const float bias0 = bias[n0 + ocol];
    const float bias1 = bias[n0 + ocol + 1];
    // loss epilogue mapping: 16 lanes/wave, rows w*2+(lane>>3), vp = lane&7
    const int lrow = w * 2 + (lane >> 3);
    const int lvp  = lane & 7;
    unsigned int* XHu = (unsigned int*)XH;
    const f32x4 zz = {0.f, 0.f, 0.f, 0.f};
    const size_t xin = (size_t)(m0 + l15) * V_SZ + v0 + quad * 8;

    // ---------------- t = 0: H_0 = tanh(Xproj_0 + bias) ----------------
    {
        float4 f0 = *(const float4*)&Xf[xin];
        float4 f1 = *(const float4*)&Xf[xin + 4];
        bf16x8 ax = cvt_bf16x8(f0, f1);
        f32x4 acc[4] = {zz, zz, zz, zz};
#pragma unroll
        for (int nt = 0; nt < 4; ++nt)
            acc[nt] = __builtin_amdgcn_mfma_f32_16x16x32_bf16(ax, bx[nt], acc[nt], 0, 0, 0);
#pragma unroll
        for (int nt = 0; nt < 4; ++nt)
#pragma unroll
            for (int r = 0; r < 4; ++r)
                red[(w * 16 + quad * 4 + r) * RSTR + nt * 16 + l15] = acc[nt][r];
        __syncthreads();
        float s0 = bias0, s1 = bias1;
#pragma unroll
        for (int w2 = 0; w2 < 8; ++w2) {
            float2 v = *(const float2*)&red[(w2 * 16 + orow) * RSTR + ocol];
            s0 += v.x; s1 += v.y;
        }
        bf16 r0 = (bf16)fast_tanh(s0);
        bf16 r1 = (bf16)fast_tanh(s1);
        unsigned int outw = (unsigned int)__builtin_bit_cast(unsigned short, r0)
                          | ((unsigned int)__builtin_bit_cast(unsigned short, r1) << 16);
        size_t oidx = (((size_t)m0 + orow) * N_SZ + n0 + ocol) >> 1;
        __hip_atomic_store(&XHu[oidx], outw, __ATOMIC_RELAXED, __HIP_MEMORY_SCOPE_AGENT);
        asm volatile("s_waitcnt vmcnt(0)" ::: "memory");
        __syncthreads();
        if (tid == 0)
            __hip_atomic_fetch_add(&gcnt[0], 1, __ATOMIC_RELAXED, __HIP_MEMORY_SCOPE_AGENT);
    }

    // ---------------- t = 1 .. 127 ----------------
    for (int t = 1; t < T_STEPS; ++t) {
        // Xproj input prefetch (fp32) + EARLY counter read (in flight during Xproj)
        float4 f0 = *(const float4*)&Xf[(size_t)t * B_SZ * V_SZ + xin];
        float4 f1 = *(const float4*)&Xf[(size_t)t * B_SZ * V_SZ + xin + 4];
        int cv = __hip_atomic_load(&gcnt[t - 1], __ATOMIC_RELAXED,
                                   __HIP_MEMORY_SCOPE_AGENT);

        // Xproj MFMAs BEFORE the poll check — absorbs the detection RTT
        bf16x8 ax = cvt_bf16x8(f0, f1);
        f32x4 acc[4] = {zz, zz, zz, zz};
#pragma unroll
        for (int nt = 0; nt < 4; ++nt)
            acc[nt] = __builtin_amdgcn_mfma_f32_16x16x32_bf16(ax, bx[nt], acc[nt], 0, 0, 0);
        asm volatile("" : "+v"(acc[0]), "+v"(acc[1]), "+v"(acc[2]), "+v"(acc[3]));

        // per-wave uniform poll (all lanes, same line => 1 txn); no release barrier.
        // WAR on red/lred vs iteration t-1 is ordered by barrier #B below.
        while (cv < NCB) {
            __builtin_amdgcn_s_sleep(1);
            cv = __hip_atomic_load(&gcnt[t - 1], __ATOMIC_RELAXED,
                                   __HIP_MEMORY_SCOPE_AGENT);
        }
        asm volatile("" ::: "memory");

        // A fragments: 16 rows of H_{t-1} (first regular-load touch => fresh from L3)
        const bf16* Ap = XH + ((size_t)(t - 1) * B_SZ + m0 + l15) * N_SZ + k0 + quad * 8;
        bf16x8 a[4];
#pragma unroll
        for (int kc = 0; kc < 4; ++kc)
            a[kc] = *(const bf16x8*)&Ap[kc * 32];

#pragma unroll
        for (int kc = 0; kc < 4; ++kc)
#pragma unroll
            for (int nt = 0; nt < 4; ++nt)
                acc[nt] = __builtin_amdgcn_mfma_f32_16x16x32_bf16(a[kc], b[nt][kc],
                                                                  acc[nt], 0, 0, 0);
        // loss MFMAs for plane t-1 (reuses a[])
        f32x4 lacc = zz;
#pragma unroll
        for (int kc = 0; kc < 4; ++kc)
            lacc = __builtin_amdgcn_mfma_f32_16x16x32_bf16(a[kc], bo[kc], lacc, 0, 0, 0);

        // both K-reduce writes in ONE window
#pragma unroll
        for (int nt = 0; nt < 4; ++nt)
#pragma unroll
            for (int r = 0; r < 4; ++r)
                red[(w * 16 + quad * 4 + r) * RSTR + nt * 16 + l15] = acc[nt][r];
#pragma unroll
        for (int r = 0; r < 4; ++r)
            lred[(w * 16 + quad * 4 + r) * LSTR + l15] = lacc[r];
        __syncthreads();   // #2: red/lred writes -> reads

        // step epilogue: reduce, tanh, publish H_t (write-through dword)
        float s0 = bias0, s1 = bias1;
#pragma unroll
        for (int w2 = 0; w2 < 8; ++w2) {
            float2 v = *(const float2*)&red[(w2 * 16 + orow) * RSTR + ocol];
            s0 += v.x; s1 += v.y;
        }
        bf16 r0 = (bf16)fast_tanh(s0);
        bf16 r1 = (bf16)fast_tanh(s1);
        unsigned int outw = (unsigned int)__builtin_bit_cast(unsigned short, r0)
                          | ((unsigned int)__builtin_bit_cast(unsigned short, r1) << 16);
        size_t oidx = (((size_t)t * B_SZ + m0 + orow) * N_SZ + n0 + ocol) >> 1;
        __hip_atomic_store(&XHu[oidx], outw, __ATOMIC_RELAXED, __HIP_MEMORY_SCOPE_AGENT);
        // pin issue order: H-store (above) must precede the logit store below, so
        // vmcnt(1) provably covers the H-store (in-order vmcnt retirement).
        asm volatile("" ::: "memory");

        // loss epilogue (16 lanes per wave, own rows; slab layout = 1 line/wave)
        if (lane < 16) {
            float sa = 0.f, sb = 0.f;
#pragma unroll
            for (int w2 = 0; w2 < 8; ++w2) {
                sa += lred[(w2 * 16 + lrow) * LSTR + lvp * 2];
                sb += lred[(w2 * 16 + lrow) * LSTR + lvp * 2 + 1];
            }
            bf16 pa = (bf16)sa, pb = (bf16)sb;
            unsigned int pw = (unsigned int)__builtin_bit_cast(unsigned short, pa)
                            | ((unsigned int)__builtin_bit_cast(unsigned short, pb) << 16);
            Lgu[(((size_t)(t - 1) * 16 + c) * B_SZ + m0 + lrow) * 8 + lvp] = pw;
        }

        // drain all but the newest VMEM op (= the logit store): H-stores complete.
        asm volatile("s_waitcnt vmcnt(1)" ::: "memory");
        __syncthreads();   // #B: all waves' H-stores drained + LDS reads done
        if (tid == 0)
            __hip_atomic_fetch_add(&gcnt[t], 1, __ATOMIC_RELAXED, __HIP_MEMORY_SCOPE_AGENT);
    }

    // ---------------- tail: loss GEMM for plane 127 ----------------
    {
        int cv = __hip_atomic_load(&gcnt[T_STEPS - 1], __ATOMIC_RELAXED,
                                   __HIP_MEMORY_SCOPE_AGENT);
        while (cv < NCB) {
            __builtin_amdgcn_s_sleep(1);
            cv = __hip_atomic_load(&gcnt[T_STEPS - 1], __ATOMIC_RELAXED,
                                   __HIP_MEMORY_SCOPE_AGENT);
        }
        asm volatile("" ::: "memory");
        const bf16* Ap = XH + ((size_t)(T_STEPS - 1) * B_SZ + m0 + l15) * N_SZ + k0 + quad * 8;
        bf16x8 a[4];
#pragma unroll
        for (int kc = 0; kc < 4; ++kc)
            a[kc] = *(const bf16x8*)&Ap[kc * 32];
        f32x4 lacc = zz;
#pragma unroll
        for (int kc = 0; kc < 4; ++kc)
            lacc = __builtin_amdgcn_mfma_f32_16x16x32_bf16(a[kc], bo[kc], lacc, 0, 0, 0);
        // WAR vs iteration-127 lred reads: all waves passed #B(127) before exiting
        // the loop, so those reads are complete — tail writes are safe.
#pragma unroll
        for (int r = 0; r < 4; ++r)
            lred[(w * 16 + quad * 4 + r) * LSTR + l15] = lacc[r];
        __syncthreads();
        if (lane < 16) {
            float sa = 0.f, sb = 0.f;
#pragma unroll
            for (int w2 = 0; w2 < 8; ++w2) {
                sa += lred[(w2 * 16 + lrow) * LSTR + lvp * 2];
                sb += lred[(w2 * 16 + lrow) * LSTR + lvp * 2 + 1];
            }
            bf16 pa = (bf16)sa, pb = (bf16)sb;
            unsigned int pw = (unsigned int)__builtin_bit_cast(unsigned short, pa)
                            | ((unsigned int)__builtin_bit_cast(unsigned short, pb) << 16);
            Lgu[(((size_t)(T_STEPS - 1) * 16 + c) * B_SZ + m0 + lrow) * 8 + lvp] = pw;
        }
    }
}

// ---------------- final: log-softmax + weighted-label loss over bf16 logits --------
// 256 blocks x 256 threads (4 waves); block handles 128 rows, wave 32 rows.
// Logits layout: [plane][cslab 16][row-in-plane 256][16 vocab] bf16.
__global__ __launch_bounds__(256) void k_lred(
    const bf16* __restrict__ Lg,
    const float* __restrict__ labels,
    const float* __restrict__ ob,
    float* __restrict__ out)
{
    __shared__ float bt[4];
    const int tid  = threadIdx.x;
    const int lane = tid & 63;
    const int w    = tid >> 6;       // 0..3
    const int cs   = lane >> 2;      // vocab slab 0..15
    const int vi   = (lane & 3) * 4; // offset in slab
    const float4 ob4 = *(const float4*)&ob[cs * 16 + vi];

    float wtot = 0.f;
    for (int i = 0; i < 32; ++i) {
        int row  = blockIdx.x * 128 + w * 32 + i;
        int p    = row >> 8;
        int brow = row & 255;
        bf16x4 lv = *(const bf16x4*)&Lg[(((size_t)p * 16 + cs) * B_SZ + brow) * 16 + vi];
        float l0 = (float)lv.x + ob4.x;
        float l1 = (float)lv.y + ob4.y;
        float l2 = (float)lv.z + ob4.z;
        float l3 = (float)lv.w + ob4.w;
        float mx = fmaxf(fmaxf(l0, l1), fmaxf(l2, l3));
#pragma unroll
        for (int sft = 1; sft < 64; sft <<= 1)
            mx = fmaxf(mx, __shfl_xor(mx, sft, 64));
        float sume = __expf(l0 - mx) + __expf(l1 - mx) + __expf(l2 - mx) + __expf(l3 - mx);
        const float4 lb = *(const float4*)&labels[(size_t)row * V_SZ + cs * 16 + vi];
        float labs = lb.x + lb.y + lb.z + lb.w;
        float labv = lb.x * l0 + lb.y * l1 + lb.z * l2 + lb.w * l3;
#pragma unroll
        for (int sft = 1; sft < 64; sft <<= 1) {
            sume += __shfl_xor(sume, sft, 64);
            labs += __shfl_xor(labs, sft, 64);
            labv += __shfl_xor(labv, sft, 64);
        }
        float lse = mx + __logf(sume);
        wtot += labs * lse - labv;
    }
    if (lane == 0) bt[w] = wtot;
    __syncthreads();
    if (tid == 0)
        atomicAdd(out, (bt[0] + bt[1] + bt[2] + bt[3]) * (1.0f / (float)NROWS));
}

extern "C" void kernel_launch(void* const* d_in, const int* in_sizes, int n_in,
                              void* d_out, int out_size, void* d_ws, size_t ws_size,
                              hipStream_t stream)
{
    const float* inputs  = (const float*)d_in[0];
    const float* labels  = (const float*)d_in[1];
    const float* weights = (const float*)d_in[2];
    const float* bias    = (const float*)d_in[3];
    const float* out_w   = (const float*)d_in[4];
    const float* out_b   = (const float*)d_in[5];
    float* out = (float*)d_out;

    char* ws = (char*)d_ws;
    bf16* XH  = (bf16*)ws;  ws += (size_t)NROWS * N_SZ * 2;   // 64 MB H states
    bf16* Lg  = (bf16*)ws;  ws += (size_t)NROWS * V_SZ * 2;   // 16 MB logits (slab)
    bf16* Wxt = (bf16*)ws;  ws += (size_t)N_SZ * V_SZ * 2;    // 0.5 MB (Wx^T)
    bf16* Wht = (bf16*)ws;  ws += (size_t)N_SZ * N_SZ * 2;    // 2 MB   (Wh^T)
    bf16* Wot = (bf16*)ws;  ws += (size_t)V_SZ * N_SZ * 2;    // 0.5 MB (Wo^T)
    int*  cnt = (int*)ws;   ws += (size_t)NGRP * T_STEPS * 4; // 8 KB sync counters

    hipMemsetAsync(out, 0, sizeof(float), stream);
    hipMemsetAsync(cnt, 0, (size_t)NGRP * T_STEPS * 4, stream);

    k_prep<<<dim3(1536), 256, 0, stream>>>(weights, out_w, Wxt, Wht, Wot);

    k_rnn<<<dim3(NGRP * NCB), 512, 0, stream>>>(inputs, Wxt, Wht, Wot, bias, XH,
                                                (unsigned int*)Lg, cnt);

    k_lred<<<dim3(NROWS / 128), 256, 0, stream>>>(Lg, labels, out_b, out);
}